// Round 11
// baseline (248.841 us; speedup 1.0000x reference)
//
#include <hip/hip_runtime.h>

#define ZD 21
#define YD 256
#define XD 256
#define BD 2
#define NCIN 16
#define NC1 32
#define NC2 64
#define BN_EPS 1e-3f

// halo-padded rulebook grid: z,y,x each padded by 1 on both sides
#define ZP 23
#define YP 258
#define XP 258
#define YPXP 66564               // YP*XP
#define GRID_TOT (BD * ZP * YPXP)  // 3,061,944
#define TAILN 133647             // max KOFF + 1; always-zero region for invalid rows

typedef __attribute__((ext_vector_type(8))) short short8;
typedef __attribute__((ext_vector_type(4))) float floatx4;

// KOFF[k] = dz*YPXP + dy*XP + dx for (dz,dy,dx) in {0,1,2}^3 lexicographic.
// Zero-padded to 36: pipelined idx prefetch reads up to index 35 (conv1);
// pad entries resolve to pb+0 which is always-valid memory.
__constant__ int KOFF[36] = {
    0, 1, 2, 258, 259, 260, 516, 517, 518,
    66564, 66565, 66566, 66822, 66823, 66824, 67080, 67081, 67082,
    133128, 133129, 133130, 133386, 133387, 133388, 133644, 133645, 133646,
    0, 0, 0, 0, 0, 0, 0, 0, 0};

__device__ inline unsigned short rne_bf16(float w) {
    unsigned b = __float_as_uint(w);
    return (unsigned short)((b + 0x7FFFu + ((b >> 16) & 1u)) >> 16);
}

// Raw barrier with LDS-only drain (R10): no cross-wave VMEM communication in
// the conv loops, so vmcnt stays un-drained across barriers.
__device__ inline void lds_barrier() {
    asm volatile("s_waitcnt lgkmcnt(0)" ::: "memory");
    __builtin_amdgcn_s_barrier();
}

// Bijective XCD-chunked swizzle (8 XCDs): contiguous voxel chunk per XCD ->
// gather slice fits the 4 MB XCD-private L2 (R9: FETCH_SIZE -43%).
__device__ inline int xcd_swz(int b, int nwg) {
    const int q = nwg >> 3, r = nwg & 7;
    const int xcd = b & 7, slot = b >> 3;
    return (xcd < r ? xcd * (q + 1) : r * (q + 1) + (xcd - r) * q) + slot;
}

// Fused prep: grid scatter (+1 encoding) + feat->bf16 (rows shifted by 1, row 0
// zeroed) + f1 zero row + weight packing + out_coors tail.
// Grid must cover max(2n, m4+1) threads.
__global__ __launch_bounds__(256) void prep_k(
    const float* __restrict__ feat, const int* __restrict__ coors,
    const float* __restrict__ W1, const float* __restrict__ W2,
    const int* __restrict__ oc, const int* __restrict__ bs,
    int* __restrict__ grid, unsigned short* __restrict__ featb,
    unsigned short* __restrict__ f1,
    short* __restrict__ wp1, short* __restrict__ wp2,
    float* __restrict__ out2, int n, int m4) {
    const int i = blockIdx.x * 256 + threadIdx.x;

    if (i < n) {                          // scatter voxel id+1 (0 = empty/zero-row)
        const int4 c = ((const int4*)coors)[i];   // [b, z, y, x]
        grid[((c.x * ZP + c.y + 1) * YP + c.z + 1) * XP + c.w + 1] = i + 1;
    }
    if (i < 2 * n) {                      // feat f32 -> bf16; voxel i -> row i+1
        const float4* p = (const float4*)feat + (size_t)i * 2;
        const float4 a = p[0], b = p[1];
        short8 o;
        o[0] = (short)rne_bf16(a.x); o[1] = (short)rne_bf16(a.y);
        o[2] = (short)rne_bf16(a.z); o[3] = (short)rne_bf16(a.w);
        o[4] = (short)rne_bf16(b.x); o[5] = (short)rne_bf16(b.y);
        o[6] = (short)rne_bf16(b.z); o[7] = (short)rne_bf16(b.w);
        ((short8*)featb)[i + 2] = o;      // slot (voxel+1)*2 + half
    }
    if (i < 2) ((short8*)featb)[i] = (short8)0;   // zero row 0 of featb
    if (i < 4) ((short8*)f1)[i] = (short8)0;      // zero row 0 of f1
    if (i < 14 * 2 * 512) {               // Wp1: [pair][cb][512]
        int pair = i / 1024, r = i % 1024, cb = r / 512, e = r % 512;
        int lane = e / 8, j = e % 8, kk = (lane >> 4) * 8 + j;
        int ko = pair * 2 + (kk >> 4), ci = kk & 15, co = cb * 16 + (lane & 15);
        float w = (ko < 27) ? W1[(ko * NCIN + ci) * NC1 + co] : 0.f;
        wp1[(pair * 2 + cb) * 512 + e] = (short)rne_bf16(w);
    }
    const int t2 = i - 14 * 2 * 512;
    if (t2 >= 0 && t2 < 27 * 4 * 512) {   // Wp2: [k][cb][512]
        int k = t2 / 2048, r = t2 % 2048, cb = r / 512, e = r % 512;
        int lane = e / 8, j = e % 8, ci = (lane >> 4) * 8 + j, co = cb * 16 + (lane & 15);
        wp2[(k * 4 + cb) * 512 + e] = (short)rne_bf16(W2[(k * NC1 + ci) * NC2 + co]);
    }
    if (i < m4) out2[i] = (float)oc[i];   // out_coors passthrough
    if (i == m4) out2[m4] = (float)bs[0];
}

// conv1: wave = 32 voxels, 7 supersteps x 2 pairs, LDS weight dbuf, raw
// lgkm-barriers, XCD swizzle. A-gathers are PREDICATED (id>0): masked-off
// lanes issue no memory request -> ~7x fewer TA line-requests (the R4..R10
// common plateau is vector-memory request-rate, ~1 line/cy/CU).
// MFMAs stay unconditional (zero-fill for inactive lanes).
__global__ __launch_bounds__(256, 4) void conv1_k(
    const unsigned short* __restrict__ featb, const int* __restrict__ coors,
    const short* __restrict__ wp1,
    const float* __restrict__ g1, const float* __restrict__ b1,
    const float* __restrict__ m1, const float* __restrict__ v1,
    const int* __restrict__ gridp, unsigned short* __restrict__ f1, int n, int tail0) {
    const int tid = threadIdx.x;
    const int lane = tid & 63;
    const int quad = lane >> 4;
    const int mrow = lane & 15;
    const int bid = xcd_swz(blockIdx.x, gridDim.x);
    const int vbase = bid * 128 + (tid >> 6) * 32;
    const int ko_add = quad >> 1;     // this quad's offset within the pair
    const int ci_half = quad & 1;     // this quad's input-channel half

    __shared__ short lw[2][2048];     // [buf][2 pairs x 1024 shorts]

    int pb[2];
#pragma unroll
    for (int mt = 0; mt < 2; ++mt) {
        const int v = vbase + mt * 16 + mrow;
        if (v < n) {
            const int4 cc = ((const int4*)coors)[v];
            pb[mt] = ((cc.x * ZP + cc.y) * YP + cc.z) * XP + cc.w;
        } else {
            pb[mt] = tail0;   // always-zero tail region
        }
    }

    floatx4 d[2][2];
#pragma unroll
    for (int mt = 0; mt < 2; ++mt)
#pragma unroll
        for (int cb = 0; cb < 2; ++cb) d[mt][cb] = (floatx4){0.f, 0.f, 0.f, 0.f};

    const short8* __restrict__ wg = (const short8*)wp1;   // 128 short8 per pair

    // prologue: stage pairs 0,1 into buf0; idx pair0 -> gather A(pair0); idx pair1
    ((short8*)lw[0])[tid] = wg[tid];
    int id_c[2], id_n[2];
#pragma unroll
    for (int mt = 0; mt < 2; ++mt) id_c[mt] = gridp[pb[mt] + KOFF[ko_add]];
#pragma unroll
    for (int mt = 0; mt < 2; ++mt) id_n[mt] = gridp[pb[mt] + KOFF[2 + ko_add]];
    short8 a_c[2];
#pragma unroll
    for (int mt = 0; mt < 2; ++mt) {
        a_c[mt] = (short8)0;
        if (id_c[mt] > 0)
            a_c[mt] = *(const short8*)(featb + (unsigned)(id_c[mt] * NCIN + ci_half * 8));
    }
    lds_barrier();

    int buf = 0;
#pragma unroll 1
    for (int s = 0; s < 7; ++s) {
        short8 wreg;
#pragma unroll
        for (int p = 0; p < 2; ++p) {
            const int pr = 2 * s + p;          // current pair
            // weight global load for next superstep (issued early, p==0)
            if (p == 0 && s < 6) wreg = wg[(s + 1) * 256 + tid];

            // this pair's weight fragments from LDS
            const short8 wf0 = ((const short8*)lw[buf])[p * 128 + lane];
            const short8 wf1 = ((const short8*)lw[buf])[p * 128 + 64 + lane];

            // PREDICATED gather A for pair pr+1 (inactive lanes: no request)
            short8 a_nx[2];
#pragma unroll
            for (int mt = 0; mt < 2; ++mt) {
                a_nx[mt] = (short8)0;
                if (id_n[mt] > 0)
                    a_nx[mt] = *(const short8*)(featb + (unsigned)(id_n[mt] * NCIN + ci_half * 8));
            }

            // idx prefetch for pair pr+2 (KOFF zero-padded past 13 pairs)
            int id_f[2];
            {
                const int koff = KOFF[2 * (pr + 2) + ko_add];
#pragma unroll
                for (int mt = 0; mt < 2; ++mt) id_f[mt] = gridp[pb[mt] + koff];
            }

            // MFMA on current pair (unconditional; zeros contribute zero)
#pragma unroll
            for (int mt = 0; mt < 2; ++mt) {
                d[mt][0] = __builtin_amdgcn_mfma_f32_16x16x32_bf16(a_c[mt], wf0, d[mt][0], 0, 0, 0);
                d[mt][1] = __builtin_amdgcn_mfma_f32_16x16x32_bf16(a_c[mt], wf1, d[mt][1], 0, 0, 0);
            }
#pragma unroll
            for (int mt = 0; mt < 2; ++mt) { a_c[mt] = a_nx[mt]; id_n[mt] = id_f[mt]; }
        }
        if (s < 6) ((short8*)lw[buf ^ 1])[tid] = wreg;
        lds_barrier();
        buf ^= 1;
    }

    // C/D layout: col = lane&15 (channel), row = quad*4 + reg (voxel)
    const int col = lane & 15;
#pragma unroll
    for (int cb = 0; cb < 2; ++cb) {
        const int ch = cb * 16 + col;
        const float sc = g1[ch] * rsqrtf(v1[ch] + BN_EPS);
        const float sb = b1[ch] - m1[ch] * sc;
#pragma unroll
        for (int mt = 0; mt < 2; ++mt) {
#pragma unroll
            for (int r = 0; r < 4; ++r) {
                const int v = vbase + mt * 16 + quad * 4 + r;
                if (v < n) {
                    const float o = fmaxf(fmaf(d[mt][cb][r], sc, sb), 0.f);
                    f1[(unsigned)((v + 1) * NC1 + ch)] = rne_bf16(o);   // row v+1
                }
            }
        }
    }
}

// conv2: wave = 32 voxels, N=64, 9 supersteps x 3 taps, LDS weight dbuf,
// raw lgkm-barriers, XCD swizzle, PREDICATED A-gathers.
__global__ __launch_bounds__(256, 4) void conv2_k(
    const unsigned short* __restrict__ f1,
    const int* __restrict__ ocoors, const short* __restrict__ wp2,
    const float* __restrict__ g2, const float* __restrict__ b2,
    const float* __restrict__ m2, const float* __restrict__ v2,
    const int* __restrict__ gridp, float* __restrict__ out, int m, int tail0) {
    const int tid = threadIdx.x;
    const int lane = tid & 63;
    const int quad = lane >> 4;
    const int mrow = lane & 15;
    const int bid = xcd_swz(blockIdx.x, gridDim.x);
    const int vbase = bid * 128 + (tid >> 6) * 32;

    __shared__ short lw[2][6144];     // [buf][3 taps x 2048 shorts]

    int pb[2];
#pragma unroll
    for (int mt = 0; mt < 2; ++mt) {
        const int v = vbase + mt * 16 + mrow;
        if (v < m) {
            const int4 cc = ((const int4*)ocoors)[v];
            pb[mt] = ((cc.x * ZP + 2 * cc.y + 1) * YP + 2 * cc.z) * XP + 2 * cc.w;
        } else {
            pb[mt] = tail0;
        }
    }

    floatx4 d[2][4];
#pragma unroll
    for (int mt = 0; mt < 2; ++mt)
#pragma unroll
        for (int cb = 0; cb < 4; ++cb) d[mt][cb] = (floatx4){0.f, 0.f, 0.f, 0.f};

    const short8* __restrict__ wg = (const short8*)wp2;   // 256 short8 per tap

    // prologue: stage taps 0..2 into buf0; idx tap0 -> gather A(tap0); idx tap1
    ((short8*)lw[0])[tid] = wg[tid];
    ((short8*)lw[0])[256 + tid] = wg[256 + tid];
    ((short8*)lw[0])[512 + tid] = wg[512 + tid];
    int id_c[2], id_n[2];
#pragma unroll
    for (int mt = 0; mt < 2; ++mt) id_c[mt] = gridp[pb[mt] + KOFF[0]];
#pragma unroll
    for (int mt = 0; mt < 2; ++mt) id_n[mt] = gridp[pb[mt] + KOFF[1]];
    short8 a_c[2];
#pragma unroll
    for (int mt = 0; mt < 2; ++mt) {
        a_c[mt] = (short8)0;
        if (id_c[mt] > 0)
            a_c[mt] = *(const short8*)(f1 + (unsigned)(id_c[mt] * NC1 + quad * 8));
    }
    lds_barrier();

    int buf = 0;
#pragma unroll 1
    for (int s = 0; s < 9; ++s) {
        short8 wreg[3];
#pragma unroll
        for (int t = 0; t < 3; ++t) {
            const int tap = 3 * s + t;
            // weight global load for next superstep's tap t (staggered issue)
            if (s < 8) wreg[t] = wg[((s + 1) * 3 + t) * 256 + tid];

            // this tap's weight fragments from LDS
            short8 wf[4];
#pragma unroll
            for (int cb = 0; cb < 4; ++cb)
                wf[cb] = ((const short8*)lw[buf])[t * 256 + cb * 64 + lane];

            // PREDICATED gather A for tap+1 (inactive lanes: no request)
            short8 a_nx[2];
#pragma unroll
            for (int mt = 0; mt < 2; ++mt) {
                a_nx[mt] = (short8)0;
                if (id_n[mt] > 0)
                    a_nx[mt] = *(const short8*)(f1 + (unsigned)(id_n[mt] * NC1 + quad * 8));
            }

            // idx prefetch for tap+2 (KOFF zero-padded past 26)
            int id_f[2];
            {
                const int koff = KOFF[tap + 2];
#pragma unroll
                for (int mt = 0; mt < 2; ++mt) id_f[mt] = gridp[pb[mt] + koff];
            }

            // MFMA on current tap (unconditional)
#pragma unroll
            for (int mt = 0; mt < 2; ++mt) {
#pragma unroll
                for (int cb = 0; cb < 4; ++cb)
                    d[mt][cb] = __builtin_amdgcn_mfma_f32_16x16x32_bf16(a_c[mt], wf[cb], d[mt][cb], 0, 0, 0);
            }
#pragma unroll
            for (int mt = 0; mt < 2; ++mt) { a_c[mt] = a_nx[mt]; id_n[mt] = id_f[mt]; }
        }
        if (s < 8) {
#pragma unroll
            for (int t = 0; t < 3; ++t)
                ((short8*)lw[buf ^ 1])[t * 256 + tid] = wreg[t];
        }
        lds_barrier();
        buf ^= 1;
    }

    const int col = lane & 15;
#pragma unroll
    for (int cb = 0; cb < 4; ++cb) {
        const int ch = cb * 16 + col;
        const float sc = g2[ch] * rsqrtf(v2[ch] + BN_EPS);
        const float sb = b2[ch] - m2[ch] * sc;
#pragma unroll
        for (int mt = 0; mt < 2; ++mt) {
#pragma unroll
            for (int r = 0; r < 4; ++r) {
                const int v = vbase + mt * 16 + quad * 4 + r;
                if (v < m)
                    out[(unsigned)(v * NC2 + ch)] = fmaxf(fmaf(d[mt][cb][r], sc, sb), 0.f);
            }
        }
    }
}

extern "C" void kernel_launch(void* const* d_in, const int* in_sizes, int n_in,
                              void* d_out, int out_size, void* d_ws, size_t ws_size,
                              hipStream_t stream) {
    const float* feat  = (const float*)d_in[0];
    const int*   coors = (const int*)d_in[1];
    const int*   ocoors= (const int*)d_in[2];
    const float* W1 = (const float*)d_in[3];
    const float* g1 = (const float*)d_in[4];
    const float* b1 = (const float*)d_in[5];
    const float* m1 = (const float*)d_in[6];
    const float* v1 = (const float*)d_in[7];
    const float* W2 = (const float*)d_in[8];
    const float* g2 = (const float*)d_in[9];
    const float* b2 = (const float*)d_in[10];
    const float* m2 = (const float*)d_in[11];
    const float* v2 = (const float*)d_in[12];
    const int*   bs = (const int*)d_in[13];

    const int n = in_sizes[0] / NCIN;
    const int m = in_sizes[2] / 4;

    char* ws = (char*)d_ws;
    int* grid = (int*)ws;
    size_t off = ((size_t)(GRID_TOT + TAILN) * sizeof(int) + 255) & ~(size_t)255;
    unsigned short* featb = (unsigned short*)(ws + off);
    off += ((size_t)(n + 1) * NCIN * 2 + 255) & ~(size_t)255;   // +1 zero row
    unsigned short* f1 = (unsigned short*)(ws + off);
    off += ((size_t)(n + 1) * NC1 * 2 + 255) & ~(size_t)255;    // +1 zero row
    short* wp1 = (short*)(ws + off);
    off += (14 * 2 * 512 * 2 + 255) & ~(size_t)255;
    short* wp2 = (short*)(ws + off);

    float* out = (float*)d_out;
    float* out2 = out + (size_t)m * NC2;

    // prep must cover the LARGEST of its fused ranges: 2n (feat) vs m*4+1 (coords)
    int prep_threads = 2 * n;
    if (m * 4 + 1 > prep_threads) prep_threads = m * 4 + 1;

    hipMemsetAsync(grid, 0x00, (size_t)(GRID_TOT + TAILN) * sizeof(int), stream);
    prep_k<<<(prep_threads + 255) / 256, 256, 0, stream>>>(feat, coors, W1, W2, ocoors, bs,
                                                           grid, featb, f1, wp1, wp2, out2, n, m * 4);

    conv1_k<<<(n + 127) / 128, 256, 0, stream>>>(featb, coors, wp1, g1, b1, m1, v1,
                                                 grid, f1, n, GRID_TOT);

    conv2_k<<<(m + 127) / 128, 256, 0, stream>>>(f1, ocoors, wp2,
                                                 g2, b2, m2, v2, grid, out, m, GRID_TOT);
}

// Round 12
// 232.909 us; speedup vs baseline: 1.0684x; 1.0684x over previous
//
#include <hip/hip_runtime.h>

#define ZD 21
#define YD 256
#define XD 256
#define BD 2
#define NCIN 16
#define NC1 32
#define NC2 64
#define BN_EPS 1e-3f

// halo-padded rulebook grid: z,y,x each padded by 1 on both sides
#define ZP 23
#define YP 258
#define XP 258
#define YPXP 66564               // YP*XP
#define GRID_TOT (BD * ZP * YPXP)  // 3,061,944
#define TAILN 133647             // max KOFF + 1; always-zero region for invalid rows

typedef __attribute__((ext_vector_type(8))) short short8;
typedef __attribute__((ext_vector_type(4))) float floatx4;

// KOFF[k] = dz*YPXP + dy*XP + dx for (dz,dy,dx) in {0,1,2}^3 lexicographic; [27]=0 pad
__constant__ int KOFF[28] = {
    0, 1, 2, 258, 259, 260, 516, 517, 518,
    66564, 66565, 66566, 66822, 66823, 66824, 67080, 67081, 67082,
    133128, 133129, 133130, 133386, 133387, 133388, 133644, 133645, 133646,
    0};

__device__ inline unsigned short rne_bf16(float w) {
    unsigned b = __float_as_uint(w);
    return (unsigned short)((b + 0x7FFFu + ((b >> 16) & 1u)) >> 16);
}

// Raw barrier with LDS-only drain (R10): no cross-wave VMEM communication in
// the conv loops, so vmcnt stays un-drained across barriers.
__device__ inline void lds_barrier() {
    asm volatile("s_waitcnt lgkmcnt(0)" ::: "memory");
    __builtin_amdgcn_s_barrier();
}

// Bijective XCD-chunked swizzle (8 XCDs): contiguous voxel chunk per XCD ->
// gather slice mostly fits the 4 MB XCD-private L2 (R9: FETCH_SIZE -43%).
__device__ inline int xcd_swz(int b, int nwg) {
    const int q = nwg >> 3, r = nwg & 7;
    const int xcd = b & 7, slot = b >> 3;
    return (xcd < r ? xcd * (q + 1) : r * (q + 1) + (xcd - r) * q) + slot;
}

// Fused prep: grid scatter (+1 encoding) + feat->bf16 (rows shifted by 1, row 0
// zeroed) + f1 zero row + weight packing + out_coors tail.
__global__ __launch_bounds__(256) void prep_k(
    const float* __restrict__ feat, const int* __restrict__ coors,
    const float* __restrict__ W1, const float* __restrict__ W2,
    const int* __restrict__ oc, const int* __restrict__ bs,
    int* __restrict__ grid, unsigned short* __restrict__ featb,
    unsigned short* __restrict__ f1,
    short* __restrict__ wp1, short* __restrict__ wp2,
    float* __restrict__ out2, int n, int m4) {
    const int i = blockIdx.x * 256 + threadIdx.x;

    if (i < n) {                          // scatter voxel id+1 (0 = empty/zero-row)
        const int4 c = ((const int4*)coors)[i];   // [b, z, y, x]
        grid[((c.x * ZP + c.y + 1) * YP + c.z + 1) * XP + c.w + 1] = i + 1;
    }
    if (i < 2 * n) {                      // feat f32 -> bf16; voxel i -> row i+1
        const float4* p = (const float4*)feat + (size_t)i * 2;
        const float4 a = p[0], b = p[1];
        short8 o;
        o[0] = (short)rne_bf16(a.x); o[1] = (short)rne_bf16(a.y);
        o[2] = (short)rne_bf16(a.z); o[3] = (short)rne_bf16(a.w);
        o[4] = (short)rne_bf16(b.x); o[5] = (short)rne_bf16(b.y);
        o[6] = (short)rne_bf16(b.z); o[7] = (short)rne_bf16(b.w);
        ((short8*)featb)[i + 2] = o;      // slot (voxel+1)*2 + half
    }
    if (i < 2) ((short8*)featb)[i] = (short8)0;   // zero row 0 of featb
    if (i < 4) ((short8*)f1)[i] = (short8)0;      // zero row 0 of f1
    if (i < 14 * 2 * 512) {               // Wp1: [pair][cb][512]
        int pair = i / 1024, r = i % 1024, cb = r / 512, e = r % 512;
        int lane = e / 8, j = e % 8, kk = (lane >> 4) * 8 + j;
        int ko = pair * 2 + (kk >> 4), ci = kk & 15, co = cb * 16 + (lane & 15);
        float w = (ko < 27) ? W1[(ko * NCIN + ci) * NC1 + co] : 0.f;
        wp1[(pair * 2 + cb) * 512 + e] = (short)rne_bf16(w);
    }
    const int t2 = i - 14 * 2 * 512;
    if (t2 >= 0 && t2 < 27 * 4 * 512) {   // Wp2: [k][cb][512]
        int k = t2 / 2048, r = t2 % 2048, cb = r / 512, e = r % 512;
        int lane = e / 8, j = e % 8, ci = (lane >> 4) * 8 + j, co = cb * 16 + (lane & 15);
        wp2[(k * 4 + cb) * 512 + e] = (short)rne_bf16(W2[(k * NC1 + ci) * NC2 + co]);
    }
    if (i < m4) out2[i] = (float)oc[i];   // out_coors passthrough
    if (i == m4) out2[m4] = (float)bs[0];
}

// conv1: 7 supersteps x 2 pairs. idx batches issued ONE SUPERSTEP AHEAD in a
// dedicated block (before any A-gather of the superstep) so, under in-order
// vmcnt completion, idx never chains behind A-gathers. Depth-2 A rotation
// (static slot p). LDS weight dbuf + lgkm-only barriers + XCD swizzle.
__global__ __launch_bounds__(256, 4) void conv1_k(
    const unsigned short* __restrict__ featb, const int* __restrict__ coors,
    const short* __restrict__ wp1,
    const float* __restrict__ g1, const float* __restrict__ b1,
    const float* __restrict__ m1, const float* __restrict__ v1,
    const int* __restrict__ gridp, unsigned short* __restrict__ f1, int n, int tail0) {
    const int tid = threadIdx.x;
    const int lane = tid & 63;
    const int quad = lane >> 4;
    const int mrow = lane & 15;
    const int bid = xcd_swz(blockIdx.x, gridDim.x);
    const int vbase = bid * 128 + (tid >> 6) * 32;
    const int ko_add = quad >> 1;     // this quad's offset within the pair
    const int ci_half = quad & 1;     // this quad's input-channel half

    __shared__ short lw[2][2048];     // [buf][2 pairs x 1024 shorts]

    int pb[2];
#pragma unroll
    for (int mt = 0; mt < 2; ++mt) {
        const int v = vbase + mt * 16 + mrow;
        if (v < n) {
            const int4 cc = ((const int4*)coors)[v];
            pb[mt] = ((cc.x * ZP + cc.y) * YP + cc.z) * XP + cc.w;
        } else {
            pb[mt] = tail0;   // always-zero tail region
        }
    }

    floatx4 d[2][2];
#pragma unroll
    for (int mt = 0; mt < 2; ++mt)
#pragma unroll
        for (int cb = 0; cb < 2; ++cb) d[mt][cb] = (floatx4){0.f, 0.f, 0.f, 0.f};

    const short8* __restrict__ wg = (const short8*)wp1;   // 256 short8 per superstep

    // weights superstep 0 -> buf0
    ((short8*)lw[0])[tid] = wg[tid];

    // idx batch superstep 0 (pairs 0,1) then superstep 1 (pairs 2,3)
    int idc[2][2], idn[2][2];
#pragma unroll
    for (int p = 0; p < 2; ++p)
#pragma unroll
        for (int mt = 0; mt < 2; ++mt)
            idc[p][mt] = gridp[pb[mt] + KOFF[2 * p + ko_add]];
#pragma unroll
    for (int p = 0; p < 2; ++p)
#pragma unroll
        for (int mt = 0; mt < 2; ++mt)
            idn[p][mt] = gridp[pb[mt] + KOFF[2 * (2 + p) + ko_add]];

    // A prologue: pairs 0,1 (unconditional; row 0 = zeros)
    short8 a[2][2];
#pragma unroll
    for (int p = 0; p < 2; ++p)
#pragma unroll
        for (int mt = 0; mt < 2; ++mt)
            a[p][mt] = *(const short8*)(featb + (unsigned)(idc[p][mt] * NCIN + ci_half * 8));
    lds_barrier();

    int buf = 0;
#pragma unroll 1
    for (int s = 0; s < 7; ++s) {
        // idx batch for superstep s+2 (pairs 2(s+2)+p), issued FIRST
        int idf[2][2];
        if (s < 5) {
#pragma unroll
            for (int p = 0; p < 2; ++p)
#pragma unroll
                for (int mt = 0; mt < 2; ++mt)
                    idf[p][mt] = gridp[pb[mt] + KOFF[4 * s + 8 + 2 * p + ko_add]];
        }
        // weights for superstep s+1
        short8 wreg;
        if (s < 6) wreg = wg[(s + 1) * 256 + tid];

#pragma unroll
        for (int p = 0; p < 2; ++p) {
            const short8 wf0 = ((const short8*)lw[buf])[p * 128 + lane];
            const short8 wf1 = ((const short8*)lw[buf])[p * 128 + 64 + lane];
#pragma unroll
            for (int mt = 0; mt < 2; ++mt) {
                d[mt][0] = __builtin_amdgcn_mfma_f32_16x16x32_bf16(a[p][mt], wf0, d[mt][0], 0, 0, 0);
                d[mt][1] = __builtin_amdgcn_mfma_f32_16x16x32_bf16(a[p][mt], wf1, d[mt][1], 0, 0, 0);
            }
            // gather pair 2(s+1)+p into slot p (consumed above; idx long completed)
            if (s < 6) {
#pragma unroll
                for (int mt = 0; mt < 2; ++mt)
                    a[p][mt] = *(const short8*)(featb + (unsigned)(idn[p][mt] * NCIN + ci_half * 8));
            }
        }
        if (s < 6) ((short8*)lw[buf ^ 1])[tid] = wreg;
        lds_barrier();
        if (s < 5) {
#pragma unroll
            for (int p = 0; p < 2; ++p)
#pragma unroll
                for (int mt = 0; mt < 2; ++mt) idn[p][mt] = idf[p][mt];
        }
        buf ^= 1;
    }

    // C/D layout: col = lane&15 (channel), row = quad*4 + reg (voxel)
    const int col = lane & 15;
#pragma unroll
    for (int cb = 0; cb < 2; ++cb) {
        const int ch = cb * 16 + col;
        const float sc = g1[ch] * rsqrtf(v1[ch] + BN_EPS);
        const float sb = b1[ch] - m1[ch] * sc;
#pragma unroll
        for (int mt = 0; mt < 2; ++mt) {
#pragma unroll
            for (int r = 0; r < 4; ++r) {
                const int v = vbase + mt * 16 + quad * 4 + r;
                if (v < n) {
                    const float o = fmaxf(fmaf(d[mt][cb][r], sc, sb), 0.f);
                    f1[(unsigned)((v + 1) * NC1 + ch)] = rne_bf16(o);   // row v+1
                }
            }
        }
    }
}

// conv2: 9 supersteps x 3 taps. idx batch one superstep ahead; depth-3 A
// rotation (static slot t); LDS weight dbuf + lgkm-only barriers + swizzle.
__global__ __launch_bounds__(256, 3) void conv2_k(
    const unsigned short* __restrict__ f1,
    const int* __restrict__ ocoors, const short* __restrict__ wp2,
    const float* __restrict__ g2, const float* __restrict__ b2,
    const float* __restrict__ m2, const float* __restrict__ v2,
    const int* __restrict__ gridp, float* __restrict__ out, int m, int tail0) {
    const int tid = threadIdx.x;
    const int lane = tid & 63;
    const int quad = lane >> 4;
    const int mrow = lane & 15;
    const int bid = xcd_swz(blockIdx.x, gridDim.x);
    const int vbase = bid * 128 + (tid >> 6) * 32;

    __shared__ short lw[2][6144];     // [buf][3 taps x 2048 shorts]

    int pb[2];
#pragma unroll
    for (int mt = 0; mt < 2; ++mt) {
        const int v = vbase + mt * 16 + mrow;
        if (v < m) {
            const int4 cc = ((const int4*)ocoors)[v];
            pb[mt] = ((cc.x * ZP + 2 * cc.y + 1) * YP + 2 * cc.z) * XP + 2 * cc.w;
        } else {
            pb[mt] = tail0;
        }
    }

    floatx4 d[2][4];
#pragma unroll
    for (int mt = 0; mt < 2; ++mt)
#pragma unroll
        for (int cb = 0; cb < 4; ++cb) d[mt][cb] = (floatx4){0.f, 0.f, 0.f, 0.f};

    const short8* __restrict__ wg = (const short8*)wp2;   // 768 short8 per superstep

    // weights superstep 0 -> buf0
    ((short8*)lw[0])[tid] = wg[tid];
    ((short8*)lw[0])[256 + tid] = wg[256 + tid];
    ((short8*)lw[0])[512 + tid] = wg[512 + tid];

    // idx batch superstep 0 (taps 0-2) then superstep 1 (taps 3-5)
    int idc[3][2], idn[3][2];
#pragma unroll
    for (int t = 0; t < 3; ++t)
#pragma unroll
        for (int mt = 0; mt < 2; ++mt) idc[t][mt] = gridp[pb[mt] + KOFF[t]];
#pragma unroll
    for (int t = 0; t < 3; ++t)
#pragma unroll
        for (int mt = 0; mt < 2; ++mt) idn[t][mt] = gridp[pb[mt] + KOFF[3 + t]];

    // A prologue: taps 0..2 (unconditional; row 0 = zeros)
    short8 a[3][2];
#pragma unroll
    for (int t = 0; t < 3; ++t)
#pragma unroll
        for (int mt = 0; mt < 2; ++mt)
            a[t][mt] = *(const short8*)(f1 + (unsigned)(idc[t][mt] * NC1 + quad * 8));
    lds_barrier();

    int buf = 0;
#pragma unroll 1
    for (int s = 0; s < 9; ++s) {
        // idx batch for superstep s+2 (taps 3(s+2)+t), issued FIRST
        int idf[3][2];
        if (s < 7) {
#pragma unroll
            for (int t = 0; t < 3; ++t)
#pragma unroll
                for (int mt = 0; mt < 2; ++mt)
                    idf[t][mt] = gridp[pb[mt] + KOFF[3 * s + 6 + t]];
        }
        // weights for superstep s+1
        short8 wreg[3];
        if (s < 8) {
#pragma unroll
            for (int t = 0; t < 3; ++t) wreg[t] = wg[((s + 1) * 3 + t) * 256 + tid];
        }

#pragma unroll
        for (int t = 0; t < 3; ++t) {
            short8 wf[4];
#pragma unroll
            for (int cb = 0; cb < 4; ++cb)
                wf[cb] = ((const short8*)lw[buf])[t * 256 + cb * 64 + lane];
#pragma unroll
            for (int mt = 0; mt < 2; ++mt) {
#pragma unroll
                for (int cb = 0; cb < 4; ++cb)
                    d[mt][cb] = __builtin_amdgcn_mfma_f32_16x16x32_bf16(a[t][mt], wf[cb], d[mt][cb], 0, 0, 0);
            }
            // gather tap 3(s+1)+t into slot t (idx long completed)
            if (s < 8) {
#pragma unroll
                for (int mt = 0; mt < 2; ++mt)
                    a[t][mt] = *(const short8*)(f1 + (unsigned)(idn[t][mt] * NC1 + quad * 8));
            }
        }
        if (s < 8) {
#pragma unroll
            for (int t = 0; t < 3; ++t)
                ((short8*)lw[buf ^ 1])[t * 256 + tid] = wreg[t];
        }
        lds_barrier();
        if (s < 7) {
#pragma unroll
            for (int t = 0; t < 3; ++t)
#pragma unroll
                for (int mt = 0; mt < 2; ++mt) idn[t][mt] = idf[t][mt];
        }
        buf ^= 1;
    }

    const int col = lane & 15;
#pragma unroll
    for (int cb = 0; cb < 4; ++cb) {
        const int ch = cb * 16 + col;
        const float sc = g2[ch] * rsqrtf(v2[ch] + BN_EPS);
        const float sb = b2[ch] - m2[ch] * sc;
#pragma unroll
        for (int mt = 0; mt < 2; ++mt) {
#pragma unroll
            for (int r = 0; r < 4; ++r) {
                const int v = vbase + mt * 16 + quad * 4 + r;
                if (v < m)
                    out[(unsigned)(v * NC2 + ch)] = fmaxf(fmaf(d[mt][cb][r], sc, sb), 0.f);
            }
        }
    }
}

extern "C" void kernel_launch(void* const* d_in, const int* in_sizes, int n_in,
                              void* d_out, int out_size, void* d_ws, size_t ws_size,
                              hipStream_t stream) {
    const float* feat  = (const float*)d_in[0];
    const int*   coors = (const int*)d_in[1];
    const int*   ocoors= (const int*)d_in[2];
    const float* W1 = (const float*)d_in[3];
    const float* g1 = (const float*)d_in[4];
    const float* b1 = (const float*)d_in[5];
    const float* m1 = (const float*)d_in[6];
    const float* v1 = (const float*)d_in[7];
    const float* W2 = (const float*)d_in[8];
    const float* g2 = (const float*)d_in[9];
    const float* b2 = (const float*)d_in[10];
    const float* m2 = (const float*)d_in[11];
    const float* v2 = (const float*)d_in[12];
    const int*   bs = (const int*)d_in[13];

    const int n = in_sizes[0] / NCIN;
    const int m = in_sizes[2] / 4;

    char* ws = (char*)d_ws;
    int* grid = (int*)ws;
    size_t off = ((size_t)(GRID_TOT + TAILN) * sizeof(int) + 255) & ~(size_t)255;
    unsigned short* featb = (unsigned short*)(ws + off);
    off += ((size_t)(n + 1) * NCIN * 2 + 255) & ~(size_t)255;   // +1 zero row
    unsigned short* f1 = (unsigned short*)(ws + off);
    off += ((size_t)(n + 1) * NC1 * 2 + 255) & ~(size_t)255;    // +1 zero row
    short* wp1 = (short*)(ws + off);
    off += (14 * 2 * 512 * 2 + 255) & ~(size_t)255;
    short* wp2 = (short*)(ws + off);

    float* out = (float*)d_out;
    float* out2 = out + (size_t)m * NC2;

    // prep must cover the LARGEST of its fused ranges: 2n (feat) vs m*4+1 (coords)
    int prep_threads = 2 * n;
    if (m * 4 + 1 > prep_threads) prep_threads = m * 4 + 1;

    hipMemsetAsync(grid, 0x00, (size_t)(GRID_TOT + TAILN) * sizeof(int), stream);
    prep_k<<<(prep_threads + 255) / 256, 256, 0, stream>>>(feat, coors, W1, W2, ocoors, bs,
                                                           grid, featb, f1, wp1, wp2, out2, n, m * 4);

    conv1_k<<<(n + 127) / 128, 256, 0, stream>>>(featb, coors, wp1, g1, b1, m1, v1,
                                                 grid, f1, n, GRID_TOT);

    conv2_k<<<(m + 127) / 128, 256, 0, stream>>>(f1, ocoors, wp2,
                                                 g2, b2, m2, v2, grid, out, m, GRID_TOT);
}